// Round 4
// baseline (670.911 us; speedup 1.0000x reference)
//
#include <hip/hip_runtime.h>

// Batched Hungarian matcher (Jonker-Volgenant shortest augmenting path),
// bit-exact vs the numpy reference given identical f32 costs.
//
// R4: f32-filtered full scan + exact lazy resolution.
// Per pop: (1) all 512 threads relax row i over their 8 columns in f32 only,
// maintaining shr32lo[j] = provable LOWER bound of shortest[j] (r32 - delta,
// delta >= 20x the worst f32-vs-f64 evaluation gap); block-min -> win32lo.
// (2) contenders = { j : shr32lo[j] <= win32lo + 2*deltamax } provably
// contains every column whose TRUE (f64, numpy-ordered) shortest equals the
// true minimum. Each thread exact-resolves its own contenders against the
// recorded scanned-row list (row, frozen minv) -> exact value + exact
// predecessor (first strict improver, numpy semantics). Block lex-argmin of
// exact values (tie -> lowest j) == numpy's pop. Duals use only recorded
// exact pop values -> bit-exact u, v forever. 2 barriers per pop.

#define Bb 32
#define Nn 4096
#define Mm 128
#define Tt 512
#define Kk (Nn / Tt)   // 8 columns per thread
#define TSH 9          // log2(Tt)
#define NW (Tt / 64)   // 8 waves
#define RECMAX 160

__global__ __launch_bounds__(Tt, 1)
void hungarian_kernel(const float* __restrict__ predict_scores,
                      const float* __restrict__ predict_points,
                      const int*   __restrict__ scores,
                      const float* __restrict__ points,
                      int* __restrict__ out)
{
    __shared__ double vvl[Nn];           // column duals (exact f64)
    __shared__ short  path_lds[Nn];      // predecessor (written only at pops)
    __shared__ short  row4col[Nn];       // matched row per column (-1 = free)
    __shared__ double uu[Mm];            // row duals
    __shared__ short  col4row[Mm];       // matched column per row (-1 = free)
    __shared__ double srow_val[Mm];      // minv when row was scanned
    __shared__ unsigned char SRr[Mm];    // scanned-row flags
    __shared__ float  tx0[Mm], tx1[Mm];
    __shared__ int    tch[Mm];
    __shared__ short  prow[RECMAX];      // scanned-row records (this search)
    __shared__ double pminv[RECMAX];     // frozen minv at scan of prow[s]
    __shared__ short  pcol[RECMAX];      // popped columns (this search)
    __shared__ double pval[RECMAX];      // their exact pop values
    __shared__ float  wf[2][NW];         // parity-buffered f32 min reduce
    __shared__ double wd[2][NW];         // parity-buffered exact argmin reduce
    __shared__ int    wc[2][NW], wp[2][NW];

    const int b   = blockIdx.x;
    const int tid = threadIdx.x;
    const double INFD = __builtin_inf();
    const float  INFF = __builtin_inff();

    // ---- per-column (prediction) data -> registers ----
    float negp0[Kk], negp1[Kk], qx0[Kk], qx1[Kk], v32[Kk], shr[Kk];
    const float* ps = predict_scores + (size_t)b * Nn * 2;
    const float* pp = predict_points + (size_t)b * Nn * 2;
    #pragma unroll
    for (int k = 0; k < Kk; ++k) {
        int j = tid + (k << TSH);
        float s0 = ps[2 * j], s1 = ps[2 * j + 1];
        float mx = fmaxf(s0, s1);
        float e0 = expf(s0 - mx), e1 = expf(s1 - mx);
        float sm = e0 + e1;
        negp0[k] = -(e0 / sm);
        negp1[k] = -(e1 / sm);
        qx0[k] = pp[2 * j];
        qx1[k] = pp[2 * j + 1];
        v32[k] = 0.0f;
        vvl[j] = 0.0;
        row4col[j] = -1;
    }
    if (tid < Mm) {
        uu[tid] = 0.0;
        col4row[tid] = -1;
        SRr[tid] = 0;
        tx0[tid] = points[(size_t)b * Mm * 2 + 2 * tid];
        tx1[tid] = points[(size_t)b * Mm * 2 + 2 * tid + 1];
        tch[tid] = scores[(size_t)b * Mm + tid];
    }
    __syncthreads();

    float Vcap = 0.0f;   // uniform upper bound on |v_j| (all j), f32

    // ---- JV outer loop over rows (targets) ----
    for (int cur_row = 0; cur_row < Mm; ++cur_row) {
        #pragma unroll
        for (int k = 0; k < Kk; ++k) shr[k] = INFF;
        unsigned scmask = 0;
        int    i = cur_row, Srow = 1, Spop = 0, sink = -1, p = 0;
        double minv = 0.0;
        float  deltamax = 0.0f;
        if (tid == 0) { prow[0] = (short)cur_row; pminv[0] = 0.0; } // covered by B1

        for (int pops = 0; pops < RECMAX - 8; ++pops) {
            // ---- (1) f32 relax of row i: registers only, no LDS ----
            const double ui = uu[i];
            const float  t0 = tx0[i], t1 = tx1[i];
            const int    ch = tch[i];
            const float  base32 = (float)(minv - ui);
            float delta = 3e-6f * (fabsf((float)minv) + fabsf((float)ui) + 4.0f + Vcap);
            deltamax = fmaxf(deltamax, delta);
            float acc = INFF;
            #pragma unroll
            for (int k = 0; k < Kk; ++k) {
                float pres = (ch == 1) ? negp1[k] : negp0[k];
                float l1   = fabsf(qx0[k] - t0) + fabsf(qx1[k] - t1);
                float r32  = (base32 + (pres + l1)) - v32[k];
                float lo   = r32 - delta;
                bool  scn  = (scmask >> k) & 1u;
                lo = scn ? INFF : lo;
                shr[k] = fminf(shr[k], lo);
                acc = fminf(acc, shr[k]);
            }
            #pragma unroll
            for (int off = 32; off > 0; off >>= 1)
                acc = fminf(acc, __shfl_xor(acc, off));
            if ((tid & 63) == 0) wf[p][tid >> 6] = acc;
            __syncthreads();                               // B1
            float win = wf[p][0];
            #pragma unroll
            for (int w = 1; w < NW; ++w) win = fminf(win, wf[p][w]);
            const float thresh = win + 2.0f * deltamax;

            // ---- (2) exact self-resolve of this thread's contenders ----
            double bv = INFD; int bj = Nn, bpred = -1;
            #pragma unroll
            for (int k = 0; k < Kk; ++k) {
                if (shr[k] <= thresh) {                    // provable superset
                    int j = tid + (k << TSH);
                    double vj = vvl[j];
                    double sv = INFD; int pr = -1;
                    for (int s = 0; s < Srow; ++s) {       // scan order, strict <
                        int rw = prow[s];
                        float rpres = (tch[rw] == 1) ? negp1[k] : negp0[k];
                        float rl1 = fabsf(qx0[k] - tx0[rw]) + fabsf(qx1[k] - tx1[rw]);
                        float cf = rpres + rl1;            // exact f32 cost (as ref)
                        double r = ((pminv[s] + (double)cf) - uu[rw]) - vj; // exact f64
                        if (r < sv) { sv = r; pr = rw; }
                    }
                    if (sv < bv) { bv = sv; bj = j; bpred = pr; } // k asc => lowest j
                }
            }
            #pragma unroll
            for (int off = 32; off > 0; off >>= 1) {
                double ov = __shfl_xor(bv, off);
                int    oj = __shfl_xor(bj, off);
                int    op2 = __shfl_xor(bpred, off);
                if (ov < bv || (ov == bv && oj < bj)) { bv = ov; bj = oj; bpred = op2; }
            }
            if ((tid & 63) == 0) {
                wd[p][tid >> 6] = bv; wc[p][tid >> 6] = bj; wp[p][tid >> 6] = bpred;
            }
            __syncthreads();                               // B2
            double best = wd[p][0]; int bestj = wc[p][0], bestp = wp[p][0];
            #pragma unroll
            for (int w = 1; w < NW; ++w) {
                double ov = wd[p][w]; int oj = wc[p][w];
                if (ov < best || (ov == best && oj < bestj)) {
                    best = ov; bestj = oj; bestp = wp[p][w];
                }
            }
            p ^= 1;
            minv = best;                                   // exact numpy pop value
            int r4 = row4col[bestj];                       // broadcast read
            if ((bestj & (Tt - 1)) == tid) {               // owner excludes column
                scmask |= 1u << (bestj >> TSH);
                shr[bestj >> TSH] = INFF;
            }
            if (tid == 0) {                                // appends: covered by next B1
                path_lds[bestj] = (short)bestp;
                pcol[Spop] = (short)bestj; pval[Spop] = best;
                if (r4 >= 0) {
                    prow[Srow] = (short)r4; pminv[Srow] = best;
                    SRr[r4] = 1; srow_val[r4] = best;
                }
            }
            Spop++;
            if (r4 < 0) { sink = bestj; break; }
            Srow++;
            i = r4;
        }
        __syncthreads();                                   // publish sink-pop records

        // ---- row end: exact dual updates + augment ----
        const double minvF = minv;
        if (tid < Mm) {
            if (tid == cur_row)   uu[tid] += minvF;
            else if (SRr[tid])    uu[tid] += minvF - srow_val[tid];
            SRr[tid] = 0;
        }
        for (int e = 0; e < Spop; ++e) {                   // owners update v + mirror
            int c = pcol[e];
            if ((c & (Tt - 1)) == tid) {
                int k = c >> TSH;
                double nv = vvl[c] - (minvF - pval[e]);    // sink: -0, no-op
                vvl[c] = nv;
                v32[k] = (float)nv;
            }
        }
        Vcap += (float)(minvF - pval[0]) + 1e-6f;          // pops nondecreasing
        if (tid == 0) {
            int j = sink;
            for (;;) {
                int i2 = path_lds[j];
                row4col[j] = (short)i2;
                int nxt = col4row[i2];
                col4row[i2] = (short)j;
                j = nxt;
                if (i2 == cur_row) break;
            }
        }
        __syncthreads();
    }

    // ---- emit (batch, src sorted ascending, tgt) ----
    if (tid < Mm) {
        int myj = col4row[tid];
        int rank = 0;
        #pragma unroll 4
        for (int t = 0; t < Mm; ++t) rank += (col4row[t] < myj) ? 1 : 0;
        out[b * Mm + tid] = b;                  // batch_idx
        out[Bb * Mm + b * Mm + rank] = myj;     // src_idx (sorted)
        out[2 * Bb * Mm + b * Mm + rank] = tid; // tgt_idx
    }
}

extern "C" void kernel_launch(void* const* d_in, const int* in_sizes, int n_in,
                              void* d_out, int out_size, void* d_ws, size_t ws_size,
                              hipStream_t stream) {
    (void)in_sizes; (void)n_in; (void)d_ws; (void)ws_size; (void)out_size;
    const float* predict_scores = (const float*)d_in[0];
    const float* predict_points = (const float*)d_in[1];
    const int*   scores         = (const int*)d_in[2];
    const float* points         = (const float*)d_in[3];
    int* out = (int*)d_out;
    hipLaunchKernelGGL(hungarian_kernel, dim3(Bb), dim3(Tt), 0, stream,
                       predict_scores, predict_points, scores, points, out);
}

// Round 5
// 623.506 us; speedup vs baseline: 1.0760x; 1.0760x over previous
//
#include <hip/hip_runtime.h>

// Batched Hungarian matcher (Jonker-Volgenant shortest augmenting path),
// bit-exact vs the numpy reference given identical f32 costs.
//
// R5: ONE barrier per Dijkstra pop.
//  - f32 packed scan keeps shr32[j] = running min of f32 reduced costs
//    (|shr32 - true_f64| <= Dmax, uniform rigorous bound).
//  - single reduction of (min1, argmin j, min2); pop certified iff
//    min2 - min1 > 2*Dmax  => true argmin unique == j*.
//  - ALL threads redundantly exact-resolve j* (f64, numpy op order) against
//    an LDS record list of scanned rows -> exact pop value + predecessor.
//    No broadcast needed, no divergence, no second barrier.
//  - uncertified pops (rare) take an exact fallback with one extra barrier.
// Duals u,v and all pop values are exact f64 == numpy; ties (lowest j) only
// ever decided on exact values. 256 threads (4 waves), 16 cols/thread.

typedef float v2f __attribute__((ext_vector_type(2)));

#define Bb 32
#define Nn 4096
#define Mm 128
#define Tt 256
#define Kk 16          // cols per thread
#define KP 8           // v2f pairs per thread
#define TSH 8          // log2(Tt)
#define NW (Tt / 64)   // 4 waves
#define RECMAX 136     // pops per search <= M+1 = 129

static __device__ inline v2f vabs2(v2f x) {
    v2f r; r.x = __builtin_fabsf(x.x); r.y = __builtin_fabsf(x.y); return r;
}
static __device__ inline v2f vmin2(v2f a, v2f b) {
    v2f r; r.x = fminf(a.x, b.x); r.y = fminf(a.y, b.y); return r;
}

__global__ __launch_bounds__(Tt, 1)
void hungarian_kernel(const float* __restrict__ predict_scores,
                      const float* __restrict__ predict_points,
                      const int*   __restrict__ scores,
                      const float* __restrict__ points,
                      int* __restrict__ out)
{
    __shared__ double vvl[Nn];            // column duals (exact f64)
    __shared__ float  pn0l[Nn], pn1l[Nn]; // -softmax probs (f32, exact)
    __shared__ float  qx0l[Nn], qx1l[Nn]; // prediction points
    __shared__ short  path_lds[Nn];       // predecessor (written at pops)
    __shared__ short  row4col[Nn];        // matched row per column (-1 free)
    __shared__ double uu[Mm];             // row duals
    __shared__ short  col4row[Mm];        // matched column per row
    __shared__ double srow_val[Mm];       // minv when row was scanned
    __shared__ unsigned char SRr[Mm];     // scanned-row flags
    __shared__ float  tx0[Mm], tx1[Mm];
    __shared__ int    tch[Mm];
    // scanned-row records for exact resolve (independent LDS loads)
    __shared__ double rec_minv[RECMAX], rec_u[RECMAX];
    __shared__ float  rec_t0[RECMAX], rec_t1[RECMAX];
    __shared__ int    rec_ch[RECMAX];
    __shared__ short  rec_row[RECMAX];
    // popped columns (for v-dual updates)
    __shared__ short  pcol[RECMAX];
    __shared__ double pval[RECMAX];
    // parity-buffered reduction slots
    __shared__ uint4  wred[2][NW];        // certified: {m1, j1, m2, -}
    __shared__ uint4  fred[2][NW];        // fallback: {bv.lo, bv.hi, j, pred}

    const int b   = blockIdx.x;
    const int tid = threadIdx.x;
    const double INFD = __builtin_inf();
    const float  INFF = __builtin_inff();

    // ---- per-column data -> registers + LDS mirrors ----
    v2f negp0v[KP], negp1v[KP], qx0v[KP], qx1v[KP], v32v[KP], shrv[KP];
    const float* ps = predict_scores + (size_t)b * Nn * 2;
    const float* pp = predict_points + (size_t)b * Nn * 2;
    #pragma unroll
    for (int p2 = 0; p2 < KP; ++p2) {
        #pragma unroll
        for (int e = 0; e < 2; ++e) {
            int k = 2 * p2 + e;
            int j = tid + (k << TSH);
            float2 sc = ((const float2*)ps)[j];
            float mx = fmaxf(sc.x, sc.y);
            float e0 = expf(sc.x - mx), e1 = expf(sc.y - mx);
            float sm = e0 + e1;
            float n0 = -(e0 / sm), n1 = -(e1 / sm);
            float2 qp = ((const float2*)pp)[j];
            if (e == 0) {
                negp0v[p2].x = n0; negp1v[p2].x = n1;
                qx0v[p2].x = qp.x; qx1v[p2].x = qp.y;
                v32v[p2].x = 0.0f;
            } else {
                negp0v[p2].y = n0; negp1v[p2].y = n1;
                qx0v[p2].y = qp.x; qx1v[p2].y = qp.y;
                v32v[p2].y = 0.0f;
            }
            pn0l[j] = n0; pn1l[j] = n1;
            qx0l[j] = qp.x; qx1l[j] = qp.y;
            vvl[j] = 0.0;
            row4col[j] = -1;
        }
    }
    if (tid < Mm) {
        uu[tid] = 0.0;
        col4row[tid] = -1;
        SRr[tid] = 0;
        tx0[tid] = points[(size_t)b * Mm * 2 + 2 * tid];
        tx1[tid] = points[(size_t)b * Mm * 2 + 2 * tid + 1];
        tch[tid] = scores[(size_t)b * Mm + tid];
    }
    __syncthreads();

    float Vcap = 0.0f;    // uniform bound on |v_j|
    int par = 0;          // reduction-buffer parity

    // ---- JV outer loop over rows (targets) ----
    for (int cur_row = 0; cur_row < Mm; ++cur_row) {
        #pragma unroll
        for (int p2 = 0; p2 < KP; ++p2) { shrv[p2].x = INFF; shrv[p2].y = INFF; }
        int    Srow = 1, Spop = 0, sink = -1;
        double minv = 0.0;
        float  Dmax = 0.0f;
        double ui = uu[cur_row];
        float  t0 = tx0[cur_row], t1 = tx1[cur_row];
        bool   chIs1 = (tch[cur_row] == 1);
        if (tid == 0) {
            rec_minv[0] = 0.0; rec_u[0] = ui;
            rec_t0[0] = t0; rec_t1[0] = t1;
            rec_ch[0] = chIs1 ? 1 : 0; rec_row[0] = (short)cur_row;
        }

        for (int pops = 0; pops < RECMAX - 4; ++pops) {
            // ---- f32 packed relax of row i (registers only) ----
            const float base32 = (float)(minv - ui);
            float delta = 3e-6f * (fabsf((float)minv) + fabsf((float)ui) + 4.0f + Vcap);
            Dmax = fmaxf(Dmax, delta);
            v2f basev; basev.x = base32; basev.y = base32;
            v2f t0v; t0v.x = t0; t0v.y = t0;
            v2f t1v; t1v.x = t1; t1v.y = t1;
            #pragma unroll
            for (int p2 = 0; p2 < KP; ++p2) {
                v2f pres = chIs1 ? negp1v[p2] : negp0v[p2];
                v2f l1 = vabs2(qx0v[p2] - t0v) + vabs2(qx1v[p2] - t1v);
                v2f r = (basev + (pres + l1)) - v32v[p2];
                shrv[p2] = vmin2(shrv[p2], r);
            }
            // ---- per-thread (min1, j, min2) ----
            float m1 = INFF, m2 = INFF; int j1i = Nn;
            #pragma unroll
            for (int p2 = 0; p2 < KP; ++p2) {
                #pragma unroll
                for (int e = 0; e < 2; ++e) {
                    float val = (e == 0) ? shrv[p2].x : shrv[p2].y;
                    int j = tid + ((2 * p2 + e) << TSH);
                    bool lt1 = val < m1;
                    float old1 = m1;
                    m1 = lt1 ? val : m1;
                    j1i = lt1 ? j : j1i;
                    m2 = fminf(m2, lt1 ? old1 : val);
                }
            }
            // ---- wave reduce (lex min1, carry min2) ----
            #pragma unroll
            for (int off = 32; off > 0; off >>= 1) {
                float om1 = __shfl_xor(m1, off);
                int   oj  = __shfl_xor(j1i, off);
                float om2 = __shfl_xor(m2, off);
                float big = fmaxf(m1, om1);
                m2 = fminf(fminf(m2, om2), big);
                bool take = (om1 < m1) || (om1 == m1 && oj < j1i);
                m1 = take ? om1 : m1;
                j1i = take ? oj : j1i;
            }
            if ((tid & 63) == 0)
                wred[par][tid >> 6] = make_uint4(__float_as_uint(m1), (unsigned)j1i,
                                                __float_as_uint(m2), 0u);
            __syncthreads();                                   // THE barrier
            const int rp = par; par ^= 1;
            float m1g, m2g; int j1g;
            {
                uint4 q = wred[rp][0];
                m1g = __uint_as_float(q.x); j1g = (int)q.y; m2g = __uint_as_float(q.z);
                #pragma unroll
                for (int w = 1; w < NW; ++w) {
                    uint4 r = wred[rp][w];
                    float a1 = __uint_as_float(r.x); int aj = (int)r.y;
                    float a2 = __uint_as_float(r.z);
                    float big = fmaxf(m1g, a1);
                    m2g = fminf(fminf(m2g, a2), big);
                    bool take = (a1 < m1g) || (a1 == m1g && aj < j1g);
                    m1g = take ? a1 : m1g;
                    j1g = take ? aj : j1g;
                }
            }
            const bool certified = (m2g - m1g) > (2.0f * Dmax);
            double minvN; int jstar, pred;
            if (certified) {
                // ---- uniform exact resolve of j* (all threads, no comms) ----
                jstar = j1g;
                double vj = vvl[jstar];
                float c0 = pn0l[jstar], c1 = pn1l[jstar];
                float qa = qx0l[jstar], qb = qx1l[jstar];
                double sv = INFD; int pr = -1;
                for (int s = 0; s < Srow; ++s) {
                    float cf = ((rec_ch[s] == 1) ? c1 : c0)
                             + fabsf(qa - rec_t0[s]) + fabsf(qb - rec_t1[s]);
                    double r = ((rec_minv[s] + (double)cf) - rec_u[s]) - vj;
                    int rw = rec_row[s];
                    if (r < sv) { sv = r; pr = rw; }           // first strict improver
                }
                minvN = sv; pred = pr;
            } else {
                // ---- exact fallback: resolve all contenders, extra barrier ----
                float cth = m1g + 2.0f * Dmax;
                double bv = INFD; int bj = Nn, bp = -1;
                #pragma unroll
                for (int p2 = 0; p2 < KP; ++p2) {
                    #pragma unroll
                    for (int e = 0; e < 2; ++e) {
                        float sval = (e == 0) ? shrv[p2].x : shrv[p2].y;
                        if (sval <= cth) {
                            int j = tid + ((2 * p2 + e) << TSH);
                            double vj = vvl[j];
                            float c0 = (e == 0) ? negp0v[p2].x : negp0v[p2].y;
                            float c1 = (e == 0) ? negp1v[p2].x : negp1v[p2].y;
                            float qa = (e == 0) ? qx0v[p2].x : qx0v[p2].y;
                            float qb = (e == 0) ? qx1v[p2].x : qx1v[p2].y;
                            double sv = INFD; int pr = -1;
                            for (int s = 0; s < Srow; ++s) {
                                float cf = ((rec_ch[s] == 1) ? c1 : c0)
                                         + fabsf(qa - rec_t0[s]) + fabsf(qb - rec_t1[s]);
                                double r = ((rec_minv[s] + (double)cf) - rec_u[s]) - vj;
                                int rw = rec_row[s];
                                if (r < sv) { sv = r; pr = rw; }
                            }
                            if (sv < bv || (sv == bv && j < bj)) { bv = sv; bj = j; bp = pr; }
                        }
                    }
                }
                #pragma unroll
                for (int off = 32; off > 0; off >>= 1) {
                    double ov = __shfl_xor(bv, off);
                    int    oj = __shfl_xor(bj, off);
                    int    op2 = __shfl_xor(bp, off);
                    if (ov < bv || (ov == bv && oj < bj)) { bv = ov; bj = oj; bp = op2; }
                }
                if ((tid & 63) == 0) {
                    unsigned long long bb = (unsigned long long)__double_as_longlong(bv);
                    fred[par][tid >> 6] = make_uint4((unsigned)(bb & 0xffffffffull),
                                                     (unsigned)(bb >> 32),
                                                     (unsigned)bj, (unsigned)bp);
                }
                __syncthreads();                               // extra barrier (rare)
                const int rp2 = par; par ^= 1;
                uint4 q = fred[rp2][0];
                double bg = __longlong_as_double(
                    (long long)(((unsigned long long)q.y << 32) | q.x));
                int jg = (int)q.z, pg = (int)q.w;
                #pragma unroll
                for (int w = 1; w < NW; ++w) {
                    uint4 r = fred[rp2][w];
                    double ov = __longlong_as_double(
                        (long long)(((unsigned long long)r.y << 32) | r.x));
                    int oj = (int)r.z;
                    if (ov < bg || (ov == bg && oj < jg)) { bg = ov; jg = oj; pg = (int)r.w; }
                }
                minvN = bg; jstar = jg; pred = pg;
            }

            // ---- uniform pop bookkeeping ----
            int r4 = row4col[jstar];                           // broadcast read
            #pragma unroll
            for (int p2 = 0; p2 < KP; ++p2) {                  // owner poison
                if (jstar == tid + ((2 * p2)     << TSH)) { shrv[p2].x = INFF; v32v[p2].x = -1e30f; }
                if (jstar == tid + ((2 * p2 + 1) << TSH)) { shrv[p2].y = INFF; v32v[p2].y = -1e30f; }
            }
            minv = minvN;
            if (tid == 0) {
                path_lds[jstar] = (short)pred;
                pcol[Spop] = (short)jstar; pval[Spop] = minv;
            }
            Spop++;
            if (r4 < 0) { sink = jstar; break; }               // uniform exit
            double un = uu[r4];
            float t0n = tx0[r4], t1n = tx1[r4];
            int   chn = tch[r4];
            if (tid == 0) {
                SRr[r4] = 1; srow_val[r4] = minv;
                rec_minv[Srow] = minv; rec_u[Srow] = un;
                rec_t0[Srow] = t0n; rec_t1[Srow] = t1n;
                rec_ch[Srow] = chn; rec_row[Srow] = (short)r4;
            }
            Srow++;
            ui = un; t0 = t0n; t1 = t1n; chIs1 = (chn == 1);
        }
        __syncthreads();   // publish final pop's records

        // ---- row end: exact dual updates + augment ----
        const double minvF = minv;
        const int SpopL = Spop;
        if (tid < Mm) {
            if (tid == cur_row)   uu[tid] += minvF;
            else if (SRr[tid])    uu[tid] += minvF - srow_val[tid];
            SRr[tid] = 0;
        }
        for (int e = 0; e < SpopL; ++e) {                      // owners update v
            int c = pcol[e];
            if ((c & (Tt - 1)) == tid) vvl[c] -= (minvF - pval[e]);
        }
        Vcap += (float)(minvF - pval[0]) + 1e-6f;              // pops nondecreasing
        if (tid == 0 && sink >= 0) {
            int j = sink;
            for (;;) {
                int i2 = path_lds[j];
                row4col[j] = (short)i2;
                int nxt = col4row[i2];
                col4row[i2] = (short)j;
                j = nxt;
                if (i2 == cur_row) break;
            }
        }
        __syncthreads();
        // rebuild f32 v mirror from exact vvl (un-poisons popped cols)
        #pragma unroll
        for (int p2 = 0; p2 < KP; ++p2) {
            int j0 = tid + ((2 * p2) << TSH);
            int j1c = tid + ((2 * p2 + 1) << TSH);
            v32v[p2].x = (float)vvl[j0];
            v32v[p2].y = (float)vvl[j1c];
        }
    }

    // ---- emit (batch, src sorted ascending, tgt) ----
    if (tid < Mm) {
        int myj = col4row[tid];
        int rank = 0;
        #pragma unroll 4
        for (int t = 0; t < Mm; ++t) rank += (col4row[t] < myj) ? 1 : 0;
        out[b * Mm + tid] = b;                  // batch_idx
        out[Bb * Mm + b * Mm + rank] = myj;     // src_idx (sorted)
        out[2 * Bb * Mm + b * Mm + rank] = tid; // tgt_idx
    }
}

extern "C" void kernel_launch(void* const* d_in, const int* in_sizes, int n_in,
                              void* d_out, int out_size, void* d_ws, size_t ws_size,
                              hipStream_t stream) {
    (void)in_sizes; (void)n_in; (void)d_ws; (void)ws_size; (void)out_size;
    const float* predict_scores = (const float*)d_in[0];
    const float* predict_points = (const float*)d_in[1];
    const int*   scores         = (const int*)d_in[2];
    const float* points         = (const float*)d_in[3];
    int* out = (int*)d_out;
    hipLaunchKernelGGL(hungarian_kernel, dim3(Bb), dim3(Tt), 0, stream,
                       predict_scores, predict_points, scores, points, out);
}

// Round 6
// 471.352 us; speedup vs baseline: 1.4234x; 1.3228x over previous
//
#include <hip/hip_runtime.h>

// Batched Hungarian matcher — exact LSA via LAPJV-style initialization +
// Jonker-Volgenant augmentation (exact f64 on exact f32 costs).
//
// R6: instead of replicating scipy's trajectory (128 augmentation searches
// from zero duals ~= 1000 Dijkstra pops), we compute the same OPTIMAL
// assignment directly:
//   1. row reduction: u[i] = min_j cf(i,j) (exact f32 value, parallel)
//   2. greedy: each row claims its argmin column (reduced cost 0 => valid
//      partial matching with feasible duals, complementary slackness).
//      128 rows over 4096 columns => ~2 collisions expected.
//   3. JV shortest-augmenting-path (proven R2 machinery, exact f64) only
//      for unassigned rows (~2-10 searches, ~1-4 pops each).
// Unique optimum (measure-1 for continuous random costs) => output indices
// identical to scipy's.

#define Bb 32
#define Nn 4096
#define Mm 128
#define Tt 512
#define Kk (Nn / Tt)   // 8 columns per thread
#define TSH 9          // log2(Tt)
#define NW (Tt / 64)   // 8 waves
#define RECMAX 160

__global__ __launch_bounds__(Tt, 1)
void hungarian_kernel(const float* __restrict__ predict_scores,
                      const float* __restrict__ predict_points,
                      const int*   __restrict__ scores,
                      const float* __restrict__ points,
                      int* __restrict__ out)
{
    __shared__ double vvl[Nn];           // column duals (exact f64)
    __shared__ float4 cold[Nn];          // {pn0, pn1, qx0, qx1} per column
    __shared__ short  path_lds[Nn];      // predecessor row per column
    __shared__ short  row4col[Nn];       // matched row per column (-1 free)
    __shared__ double uu[Mm];            // row duals
    __shared__ short  col4row[Mm];       // matched column per row (-1 free)
    __shared__ double srow_val[Mm];      // minv when row was scanned
    __shared__ unsigned char SRr[Mm];    // scanned-row flags
    __shared__ float  tx0[Mm], tx1[Mm];
    __shared__ int    tch[Mm];
    __shared__ short  rmin_j[Mm];        // argmin column per row
    __shared__ short  scol[RECMAX];      // popped columns (this search)
    __shared__ double sval[RECMAX];      // their pop values
    __shared__ int    nsc_lds;
    __shared__ double wminb[2][NW];      // parity-buffered reduction
    __shared__ int    wjminb[2][NW];

    const int b   = blockIdx.x;
    const int tid = threadIdx.x;
    const double INFD = __builtin_inf();
    const float  INFF = __builtin_inff();

    // ---- per-column data -> registers + packed LDS ----
    float negp0[Kk], negp1[Kk], qx0[Kk], qx1[Kk];
    const float* ps = predict_scores + (size_t)b * Nn * 2;
    const float* pp = predict_points + (size_t)b * Nn * 2;
    #pragma unroll
    for (int k = 0; k < Kk; ++k) {
        int j = tid + (k << TSH);
        float2 sc = ((const float2*)ps)[j];
        float mx = fmaxf(sc.x, sc.y);
        float e0 = expf(sc.x - mx), e1 = expf(sc.y - mx);
        float sm = e0 + e1;
        float n0 = -(e0 / sm), n1 = -(e1 / sm);
        float2 qp = ((const float2*)pp)[j];
        negp0[k] = n0; negp1[k] = n1;
        qx0[k] = qp.x; qx1[k] = qp.y;
        cold[j] = make_float4(n0, n1, qp.x, qp.y);
        vvl[j] = 0.0;
        row4col[j] = -1;
    }
    if (tid < Mm) {
        col4row[tid] = -1;
        SRr[tid] = 0;
        tx0[tid] = points[(size_t)b * Mm * 2 + 2 * tid];
        tx1[tid] = points[(size_t)b * Mm * 2 + 2 * tid + 1];
        tch[tid] = scores[(size_t)b * Mm + tid];
    }
    __syncthreads();

    // ---- row reduction: wave w handles rows w*16..w*16+15 ----
    {
        const int wv = tid >> 6, lane = tid & 63;
        for (int rr = 0; rr < Mm / NW; ++rr) {
            int i = wv * (Mm / NW) + rr;
            float t0 = tx0[i], t1 = tx1[i];
            int   ch = tch[i];
            float m = INFF; int jb = 0;
            for (int t = 0; t < Nn / 64; ++t) {
                int j = lane + (t << 6);
                float4 c = cold[j];
                // exact f32 cost, numpy association: pres + (|dx| + |dy|)
                float cf = ((ch == 1) ? c.y : c.x)
                         + (fabsf(c.z - t0) + fabsf(c.w - t1));
                if (cf < m) { m = cf; jb = j; }   // j asc => lowest j on tie
            }
            #pragma unroll
            for (int off = 32; off > 0; off >>= 1) {
                float om = __shfl_xor(m, off);
                int   oj = __shfl_xor(jb, off);
                if (om < m || (om == m && oj < jb)) { m = om; jb = oj; }
            }
            if (lane == 0) { rmin_j[i] = (short)jb; uu[i] = (double)m; }
        }
    }
    __syncthreads();

    // ---- greedy: rows claim argmin columns (zero reduced cost) ----
    if (tid == 0) {
        for (int i = 0; i < Mm; ++i) {
            int j = rmin_j[i];
            if (row4col[j] < 0) { row4col[j] = (short)i; col4row[i] = (short)j; }
        }
    }
    __syncthreads();

    // ---- JV augmentation for unassigned rows only ----
    for (int cur_row = 0; cur_row < Mm; ++cur_row) {
        if (col4row[cur_row] >= 0) continue;   // uniform skip (LDS broadcast)

        double shr[Kk];
        #pragma unroll
        for (int k = 0; k < Kk; ++k) shr[k] = INFD;
        unsigned scmask = 0;
        int    i = cur_row;
        double minv = 0.0;
        int    sink = -1, par = 0, nsc = 0;

        for (;;) {
            // ---- relax row i over all 4096 columns (exact f64) ----
            const double ui = uu[i];
            const float  t0 = tx0[i], t1 = tx1[i];
            const int    ch = tch[i];
            double bv = INFD; int bj = 0;
            #pragma unroll
            for (int k = 0; k < Kk; ++k) {
                int j = tid + (k << TSH);
                float pres = (ch == 1) ? negp1[k] : negp0[k];
                float cf = pres + (fabsf(qx0[k] - t0) + fabsf(qx1[k] - t1));
                double r = ((minv + (double)cf) - ui) - vvl[j];
                bool sc = (scmask >> k) & 1u;
                if (!sc && r < shr[k]) { shr[k] = r; path_lds[j] = (short)i; }
                double sj = sc ? INFD : shr[k];
                if (sj < bv) { bv = sj; bj = j; }   // k asc => lowest j on tie
            }
            #pragma unroll
            for (int off = 32; off > 0; off >>= 1) {
                double ov = __shfl_down(bv, off);
                int    oj = __shfl_down(bj, off);
                if (ov < bv || (ov == bv && oj < bj)) { bv = ov; bj = oj; }
            }
            if ((tid & 63) == 0) { wminb[par][tid >> 6] = bv; wjminb[par][tid >> 6] = bj; }
            __syncthreads();
            double best = wminb[par][0]; int bestj = wjminb[par][0];
            #pragma unroll
            for (int w = 1; w < NW; ++w) {
                double ov = wminb[par][w]; int oj = wjminb[par][w];
                if (ov < best || (ov == best && oj < bestj)) { best = ov; bestj = oj; }
            }
            par ^= 1;
            minv = best;
            if ((bestj & (Tt - 1)) == tid) scmask |= (1u << (bestj >> TSH));
            int r4 = row4col[bestj];
            if (r4 < 0) {
                if (tid == 0) nsc_lds = nsc;
                sink = bestj;
                break;                             // uniform exit
            }
            if (tid == 0) {
                SRr[r4] = 1; srow_val[r4] = best;
                scol[nsc] = bestj; sval[nsc] = best; ++nsc;
            }
            i = r4;
        }
        __syncthreads();                           // publish nsc/SRr/records

        // ---- dual updates + augment ----
        const double minvF = minv;
        if (tid < Mm) {
            if (tid == cur_row)   uu[tid] += minvF;
            else if (SRr[tid])    uu[tid] += minvF - srow_val[tid];
            SRr[tid] = 0;
        }
        int S = nsc_lds;
        if (tid < S) {
            int jc = scol[tid];
            vvl[jc] -= (minvF - sval[tid]);
        }
        if (tid == 0) {
            int j = sink;
            for (;;) {
                int i2 = path_lds[j];
                row4col[j] = (short)i2;
                int nxt = col4row[i2];
                col4row[i2] = (short)j;
                j = nxt;
                if (i2 == cur_row) break;
            }
        }
        __syncthreads();
    }

    // ---- emit (batch, src sorted ascending, tgt) ----
    if (tid < Mm) {
        int myj = col4row[tid];
        int rank = 0;
        #pragma unroll 4
        for (int t = 0; t < Mm; ++t) rank += (col4row[t] < myj) ? 1 : 0;
        out[b * Mm + tid] = b;                  // batch_idx
        out[Bb * Mm + b * Mm + rank] = myj;     // src_idx (sorted)
        out[2 * Bb * Mm + b * Mm + rank] = tid; // tgt_idx
    }
}

extern "C" void kernel_launch(void* const* d_in, const int* in_sizes, int n_in,
                              void* d_out, int out_size, void* d_ws, size_t ws_size,
                              hipStream_t stream) {
    (void)in_sizes; (void)n_in; (void)d_ws; (void)ws_size; (void)out_size;
    const float* predict_scores = (const float*)d_in[0];
    const float* predict_points = (const float*)d_in[1];
    const int*   scores         = (const int*)d_in[2];
    const float* points         = (const float*)d_in[3];
    int* out = (int*)d_out;
    hipLaunchKernelGGL(hungarian_kernel, dim3(Bb), dim3(Tt), 0, stream,
                       predict_scores, predict_points, scores, points, out);
}